// Round 1
// baseline (301.217 us; speedup 1.0000x reference)
//
#include <hip/hip_runtime.h>
#include <hip/hip_bf16.h>
#include <math.h>

// ---------------------------------------------------------------------------
// AttentionHead: B=8, S=2048, E=1024, D=64
// R-next: barrier-free attention. K/V per batch = 512KB -> L2-resident, so
// MFMA B-fragments are loaded DIRECTLY from fragment-ordered global Kf/Vf
// (no LDS staging, no per-iteration __syncthreads/vmcnt(0) drain). Mask read
// vectorized int4 (16B/lane), prefetched 1 tile ahead, packed to zero-flag
// bits; applied via conditional P-zeroing in LDS behind a uniform __any()
// branch (dead for the all-ones bench). Grid 1024 (b=bid&7 pins batch->XCD),
// 256 thr = 4 waves x 8 K-tiles, tree combine. Fixed-max softmax as before.
// ws: Qg bf16 [B*S][64] @0MB | Kf frag @2MB | Vf frag @4MB | Wf frag @6MB
// ---------------------------------------------------------------------------

typedef __attribute__((ext_vector_type(8))) short short8;
typedef __attribute__((ext_vector_type(4))) float v4f;

__device__ __forceinline__ unsigned short f2bf(float f) {
  unsigned int u = __float_as_uint(f);
  unsigned int r = (u + 0x7fffu + ((u >> 16) & 1u)) >> 16;
  return (unsigned short)r;
}

// ---------------------------------------------------------------------------
// Kernel 1: Wf in proj fragment order (unchanged).
// ---------------------------------------------------------------------------
__global__ __launch_bounds__(256) void prep_wf(const float* __restrict__ Wq,
                                               const float* __restrict__ Wk,
                                               const float* __restrict__ Wv,
                                               unsigned short* __restrict__ Wf) {
  int o = blockIdx.x * 256 + threadIdx.x;  // 0 .. 196607
  int j = o & 7;
  int lane = (o >> 3) & 63;
  int c = o >> 9;           // kt*24 + nt*2 + kk
  int kk = c & 1;
  int nt = (c % 24) >> 1;
  int kt = c / 24;
  int q = lane & 15, quad = lane >> 4;
  int n = nt * 16 + q;
  int k = kt * 64 + kk * 32 + quad * 8 + j;
  const float* W = (n < 64) ? Wq : (n < 128 ? Wk : Wv);
  Wf[o] = f2bf(W[(size_t)k * 64 + (n & 63)]);
}

// ---------------------------------------------------------------------------
// Kernel 2: QKV projection, barrier-free. Grid 512 x 512 thr = 8 waves.
// Wave = (rg = w>>2: 16-row group) x (ng = w&3: 48 output cols = 3 n-tiles).
// B-fragments read directly from Wf (L2-resident, 384KB) - no LDS.
// ---------------------------------------------------------------------------
__global__ __launch_bounds__(512) void proj_kernel(const float* __restrict__ x,
                                                   const unsigned short* __restrict__ Wf,
                                                   unsigned short* __restrict__ Qg,
                                                   unsigned short* __restrict__ Kf,
                                                   unsigned short* __restrict__ Vf) {
  const int tid = threadIdx.x;
  const int w = tid >> 6;
  const int lane = tid & 63;
  const int q = lane & 15, quad = lane >> 4;
  const int rg = w >> 2, ng = w & 3;
  const int m0 = blockIdx.x * 32 + rg * 16;

  const float* xrow = x + (size_t)(m0 + q) * 1024 + quad * 8;
  const unsigned short* Wl = Wf + lane * 8;

  v4f acc[3];
#pragma unroll
  for (int i = 0; i < 3; i++) acc[i] = (v4f)(0.0f);

  float4 acur[4], anext[4];
  auto loadA = [&](int kt, float4 a[4]) {
    const float* p = xrow + kt * 64;
    a[0] = *reinterpret_cast<const float4*>(p);
    a[1] = *reinterpret_cast<const float4*>(p + 4);
    a[2] = *reinterpret_cast<const float4*>(p + 32);
    a[3] = *reinterpret_cast<const float4*>(p + 36);
  };

  loadA(0, acur);

  for (int kt = 0; kt < 16; kt++) {
    if (kt < 15) loadA(kt + 1, anext);
    short8 af0, af1;
    {
      float* f = reinterpret_cast<float*>(acur);
#pragma unroll
      for (int j = 0; j < 4; j++) { af0[j] = (short)f2bf(f[j]); af0[4 + j] = (short)f2bf(f[4 + j]); }
#pragma unroll
      for (int j = 0; j < 4; j++) { af1[j] = (short)f2bf(f[8 + j]); af1[4 + j] = (short)f2bf(f[12 + j]); }
    }
    __builtin_amdgcn_s_setprio(1);
#pragma unroll
    for (int i = 0; i < 3; i++) {
      const size_t toff = ((size_t)kt * 24 + (ng * 3 + i) * 2) * 512;
      short8 b0 = *reinterpret_cast<const short8*>(Wl + toff);
      short8 b1 = *reinterpret_cast<const short8*>(Wl + toff + 512);
      acc[i] = __builtin_amdgcn_mfma_f32_16x16x32_bf16(af0, b0, acc[i], 0, 0, 0);
      acc[i] = __builtin_amdgcn_mfma_f32_16x16x32_bf16(af1, b1, acc[i], 0, 0, 0);
    }
    __builtin_amdgcn_s_setprio(0);
#pragma unroll
    for (int i = 0; i < 4; i++) acur[i] = anext[i];
  }

#pragma unroll
  for (int i = 0; i < 3; i++) {
    const int n = (ng * 3 + i) * 16 + q;
#pragma unroll
    for (int r = 0; r < 4; r++) {
      const int m = m0 + quad * 4 + r;
      const unsigned short hv = f2bf(acc[i][r]);
      if (n < 64) {
        Qg[(size_t)m * 64 + n] = hv;
      } else if (n < 128) {
        const int d = n - 64, s = m;
        const int b = s >> 11, srem = s & 2047, g = srem >> 4, qi = srem & 15;
        const int kk2 = d >> 5, quad2 = (d >> 3) & 3, j2 = d & 7;
        Kf[((((size_t)b * 128 + g) * 2 + kk2) * 64 + quad2 * 16 + qi) * 8 + j2] = hv;
      } else {
        const int d = n - 128, s = m;
        const int b = s >> 11, srem = s & 2047, kt2 = srem >> 6, s6 = srem & 63;
        const int kk2 = s6 >> 5, quad2 = (s6 >> 3) & 3, j2 = s6 & 7;
        const int dt = d >> 4, qi = d & 15;
        Vf[(((((size_t)b * 32 + kt2) * 4 + dt) * 2 + kk2) * 64 + quad2 * 16 + qi) * 8 + j2] = hv;
      }
    }
  }
}

// ---------------------------------------------------------------------------
// Kernel 3: flash attention, fixed-max softmax, barrier-free main loop.
// Grid 1024 (b = bid&7 -> XCD affinity, qt = bid>>3), 256 thr = 4 waves.
// Block owns 16 q-rows; wave w owns K-tiles kt in [w*8, w*8+8).
// K/V B-fragments direct from global (L2). Mask: int4-vectorized, prefetched,
// packed to zero-bits; applied by conditional P-zeroing (uniform-skippable).
// 4-way (o,l) tree combine through LDS at the end.
// ---------------------------------------------------------------------------
__global__ __launch_bounds__(256, 3) void attn_kernel(const unsigned short* __restrict__ Qg,
                                                      const unsigned short* __restrict__ Kf,
                                                      const unsigned short* __restrict__ Vf,
                                                      const int* __restrict__ maskg,
                                                      float* __restrict__ outg) {
  __shared__ __align__(16) unsigned short Pl[4][16][72];  // 9216 B; reused as combine scratch

  const int tid = threadIdx.x;
  const int bid = blockIdx.x;
  const int b = bid & 7, qt = bid >> 3;
  const int q0 = qt * 16;
  const int w = tid >> 6, lane = tid & 63;
  const int q = lane & 15, quad = lane >> 4;

  // Q fragments (A-operand) for the block's 16 rows
  const size_t qbase = ((size_t)b * 2048 + q0 + q) * 64 + quad * 8;
  const short8 qf0 = *reinterpret_cast<const short8*>(&Qg[qbase]);
  const short8 qf1 = *reinterpret_cast<const short8*>(&Qg[qbase + 32]);

  short8 onesf;
#pragma unroll
  for (int j = 0; j < 8; j++) onesf[j] = (short)0x3F80;  // bf16 1.0

  const unsigned short* Kb = Kf + (size_t)b * 131072 + lane * 8;
  const unsigned short* Vb = Vf + (size_t)b * 131072 + lane * 8;
  // lane (q,quad), iter j covers mask[row q0 + j*4+quad][col kt*64 + q*4 .. +3]
  const int* mb = maskg + ((size_t)b * 2048 + q0 + quad) * 2048 + q * 4;

  v4f o_acc[4], l_acc;
#pragma unroll
  for (int dt = 0; dt < 4; dt++) o_acc[dt] = (v4f)(0.0f);
  l_acc = (v4f)(0.0f);

  const float SC = 0.125f * 1.4426950408889634f;  // 1/sqrt(64) * log2(e)
  const int kt0 = w * 8;

  // initial mask tile -> zero-flag bits (bit j*4+c set iff element is 0)
  unsigned zb = 0;
  {
    int4 m4[4];
#pragma unroll
    for (int j = 0; j < 4; j++)
      m4[j] = *reinterpret_cast<const int4*>(mb + (size_t)j * 8192 + kt0 * 64);
#pragma unroll
    for (int j = 0; j < 4; j++)
      zb |= ((unsigned)(m4[j].x == 0) << (j * 4)) | ((unsigned)(m4[j].y == 0) << (j * 4 + 1)) |
            ((unsigned)(m4[j].z == 0) << (j * 4 + 2)) | ((unsigned)(m4[j].w == 0) << (j * 4 + 3));
  }

#pragma unroll
  for (int it = 0; it < 8; it++) {
    const int kt = kt0 + it;

    // prefetch next tile's mask (latency hidden under this tile's MFMA/VALU)
    int4 m4[4];
    if (it < 7) {
#pragma unroll
      for (int j = 0; j < 4; j++)
        m4[j] = *reinterpret_cast<const int4*>(mb + (size_t)j * 8192 + (kt + 1) * 64);
    }

    // S = Q K^T  (K fragments direct from L2-resident Kf)
    v4f s_acc[4];
    __builtin_amdgcn_s_setprio(1);
#pragma unroll
    for (int nt = 0; nt < 4; nt++) {
      short8 k0 = *reinterpret_cast<const short8*>(Kb + ((size_t)kt * 8 + nt * 2 + 0) * 512);
      short8 k1 = *reinterpret_cast<const short8*>(Kb + ((size_t)kt * 8 + nt * 2 + 1) * 512);
      s_acc[nt] = __builtin_amdgcn_mfma_f32_16x16x32_bf16(qf0, k0, (v4f)(0.0f), 0, 0, 0);
      s_acc[nt] = __builtin_amdgcn_mfma_f32_16x16x32_bf16(qf1, k1, s_acc[nt], 0, 0, 0);
    }
    __builtin_amdgcn_s_setprio(0);

    // fixed-max softmax numerator: p = exp2(s*SC); write P row-major
#pragma unroll
    for (int nt = 0; nt < 4; nt++)
#pragma unroll
      for (int r = 0; r < 4; r++)
        Pl[w][quad * 4 + r][nt * 16 + q] = f2bf(exp2f(s_acc[nt][r] * SC));

    // apply mask by zeroing P entries (dead branch when mask is all-nonzero)
    if (__any(zb != 0u)) {
#pragma unroll
      for (int j = 0; j < 4; j++)
#pragma unroll
        for (int c = 0; c < 4; c++)
          if ((zb >> (j * 4 + c)) & 1u) Pl[w][j * 4 + quad][q * 4 + c] = 0;
    }

    // read P as A fragments (same-wave RAW through LDS: compiler inserts lgkmcnt)
    const short8 pf0 = *reinterpret_cast<const short8*>(&Pl[w][q][quad * 8]);
    const short8 pf1 = *reinterpret_cast<const short8*>(&Pl[w][q][32 + quad * 8]);

    // O += P V ; l += P * ones   (V fragments direct from L2-resident Vf)
    __builtin_amdgcn_s_setprio(1);
#pragma unroll
    for (int dt = 0; dt < 4; dt++) {
      short8 v0 = *reinterpret_cast<const short8*>(Vb + ((size_t)kt * 8 + dt * 2 + 0) * 512);
      short8 v1 = *reinterpret_cast<const short8*>(Vb + ((size_t)kt * 8 + dt * 2 + 1) * 512);
      o_acc[dt] = __builtin_amdgcn_mfma_f32_16x16x32_bf16(pf0, v0, o_acc[dt], 0, 0, 0);
      o_acc[dt] = __builtin_amdgcn_mfma_f32_16x16x32_bf16(pf1, v1, o_acc[dt], 0, 0, 0);
    }
    l_acc = __builtin_amdgcn_mfma_f32_16x16x32_bf16(pf0, onesf, l_acc, 0, 0, 0);
    l_acc = __builtin_amdgcn_mfma_f32_16x16x32_bf16(pf1, onesf, l_acc, 0, 0, 0);
    __builtin_amdgcn_s_setprio(0);

    // pack next tile's zero-bits
    if (it < 7) {
      zb = 0;
#pragma unroll
      for (int j = 0; j < 4; j++)
        zb |= ((unsigned)(m4[j].x == 0) << (j * 4)) | ((unsigned)(m4[j].y == 0) << (j * 4 + 1)) |
              ((unsigned)(m4[j].z == 0) << (j * 4 + 2)) | ((unsigned)(m4[j].w == 0) << (j * 4 + 3));
    }
  }

  // ---- tree combine of 4 waves' (o,l) through LDS (reusing Pl) ----
  __syncthreads();
  float* Osf = reinterpret_cast<float*>(&Pl[0][0][0]);  // [2][16][68] f32, 2-way-bank-safe
  float* Lsf = Osf + 2 * 16 * 68;                       // [2][16] f32

  if (w >= 2) {
    const int wi = w - 2;
#pragma unroll
    for (int r = 0; r < 4; r++) {
      const int row = quad * 4 + r;
#pragma unroll
      for (int dt = 0; dt < 4; dt++) Osf[(wi * 16 + row) * 68 + dt * 16 + q] = o_acc[dt][r];
      if (q == 0) Lsf[wi * 16 + row] = l_acc[r];
    }
  }
  __syncthreads();
  if (w < 2) {
#pragma unroll
    for (int r = 0; r < 4; r++) {
      const int row = quad * 4 + r;
#pragma unroll
      for (int dt = 0; dt < 4; dt++) o_acc[dt][r] += Osf[(w * 16 + row) * 68 + dt * 16 + q];
      l_acc[r] += Lsf[w * 16 + row];
    }
  }
  __syncthreads();
  if (w == 1) {
#pragma unroll
    for (int r = 0; r < 4; r++) {
      const int row = quad * 4 + r;
#pragma unroll
      for (int dt = 0; dt < 4; dt++) Osf[row * 68 + dt * 16 + q] = o_acc[dt][r];
      if (q == 0) Lsf[row] = l_acc[r];
    }
  }
  __syncthreads();
  if (w == 0) {
#pragma unroll
    for (int r = 0; r < 4; r++) {
      const int row = quad * 4 + r;
      const float inv = 1.0f / (l_acc[r] + Lsf[row]);
      const size_t orow = ((size_t)b * 2048 + q0 + row) * 64;
#pragma unroll
      for (int dt = 0; dt < 4; dt++)
        outg[orow + dt * 16 + q] = (o_acc[dt][r] + Osf[row * 68 + dt * 16 + q]) * inv;
    }
  }
}

// ---------------------------------------------------------------------------
extern "C" void kernel_launch(void* const* d_in, const int* in_sizes, int n_in,
                              void* d_out, int out_size, void* d_ws, size_t ws_size,
                              hipStream_t stream) {
  const float* x = (const float*)d_in[0];
  const int* mask = (const int*)d_in[1];
  const float* Wq = (const float*)d_in[2];
  const float* Wk = (const float*)d_in[3];
  const float* Wv = (const float*)d_in[4];
  float* out = (float*)d_out;

  char* ws = (char*)d_ws;
  unsigned short* Qg = (unsigned short*)(ws);
  unsigned short* Kf = (unsigned short*)(ws + (size_t)(2 << 20));
  unsigned short* Vf = (unsigned short*)(ws + (size_t)(4 << 20));
  unsigned short* Wf = (unsigned short*)(ws + (size_t)(6 << 20));

  prep_wf<<<768, 256, 0, stream>>>(Wq, Wk, Wv, Wf);
  proj_kernel<<<512, 512, 0, stream>>>(x, Wf, Qg, Kf, Vf);
  attn_kernel<<<1024, 256, 0, stream>>>(Qg, Kf, Vf, mask, out);
}

// Round 2
// 294.957 us; speedup vs baseline: 1.0212x; 1.0212x over previous
//
#include <hip/hip_runtime.h>
#include <hip/hip_bf16.h>
#include <math.h>

// ---------------------------------------------------------------------------
// AttentionHead: B=8, S=2048, E=1024, D=64
// R2: barrier-free + REGISTER PREFETCH. K/V/Wf fragments live in L2; the
// round-1 regression was exposed L2 latency (loads inside setprio regions,
// no prefetch distance after LDS staging was removed). Now:
//  - proj: 6 B-fragments double-buffered in registers, loaded one kt ahead.
//  - attn: 8 K-fragments prefetched one kt ahead; V issued before the
//    exp2+LDS P round-trip so that path hides V latency.
//  - prep_wf: coalesced float4 W reads, scattered 2B stores.
// ws: Qg bf16 [B*S][64] @0MB | Kf frag @2MB | Vf frag @4MB | Wf frag @6MB
// ---------------------------------------------------------------------------

typedef __attribute__((ext_vector_type(8))) short short8;
typedef __attribute__((ext_vector_type(4))) float v4f;

__device__ __forceinline__ unsigned short f2bf(float f) {
  unsigned int u = __float_as_uint(f);
  unsigned int r = (u + 0x7fffu + ((u >> 16) & 1u)) >> 16;
  return (unsigned short)r;
}

// ---------------------------------------------------------------------------
// Kernel 1: Wf in proj fragment order. Coalesced reads (float4/lane),
// scattered 2B stores. 192 blocks x 256 thr.
// ---------------------------------------------------------------------------
__global__ __launch_bounds__(256) void prep_wf(const float* __restrict__ Wq,
                                               const float* __restrict__ Wk,
                                               const float* __restrict__ Wv,
                                               unsigned short* __restrict__ Wf) {
  int t = blockIdx.x * 256 + threadIdx.x;  // 0..49151
  int e0 = t * 4;
  int m = e0 >> 16;      // which matrix (0..2)
  int rem = e0 & 65535;  // element within 64K-float matrix
  int k = rem >> 6, n0 = rem & 63;
  const float* W = (m == 0) ? Wq : (m == 1 ? Wk : Wv);
  float4 f4 = *reinterpret_cast<const float4*>(W + rem);
  int kt = k >> 6, rr = k & 63;
  int kk = rr >> 5, quad = (rr >> 3) & 3, j = k & 7;
  int cbase = kt * 24 + kk;
  float f[4] = {f4.x, f4.y, f4.z, f4.w};
#pragma unroll
  for (int c = 0; c < 4; c++) {
    int N = m * 64 + n0 + c;
    int nt = N >> 4, q = N & 15;
    int o = (((cbase + nt * 2) << 6) | (quad * 16 + q)) * 8 + j;
    Wf[o] = f2bf(f[c]);
  }
}

// ---------------------------------------------------------------------------
// Kernel 2: QKV projection, barrier-free, register-prefetched B.
// Grid 512 x 512 thr = 8 waves: (rg = w>>2: 16-row group) x (ng = w&3: 3
// n-tiles). B-fragments double-buffered in registers, loaded one kt ahead.
// ---------------------------------------------------------------------------
__global__ __launch_bounds__(512) void proj_kernel(const float* __restrict__ x,
                                                   const unsigned short* __restrict__ Wf,
                                                   unsigned short* __restrict__ Qg,
                                                   unsigned short* __restrict__ Kf,
                                                   unsigned short* __restrict__ Vf) {
  const int tid = threadIdx.x;
  const int w = tid >> 6;
  const int lane = tid & 63;
  const int q = lane & 15, quad = lane >> 4;
  const int rg = w >> 2, ng = w & 3;
  const int m0 = blockIdx.x * 32 + rg * 16;

  const float* xrow = x + (size_t)(m0 + q) * 1024 + quad * 8;
  const unsigned short* Wl = Wf + lane * 8;

  v4f acc[3];
#pragma unroll
  for (int i = 0; i < 3; i++) acc[i] = (v4f)(0.0f);

  float4 acur[4], anext[4];
  auto loadA = [&](int kt, float4 a[4]) {
    const float* p = xrow + kt * 64;
    a[0] = *reinterpret_cast<const float4*>(p);
    a[1] = *reinterpret_cast<const float4*>(p + 4);
    a[2] = *reinterpret_cast<const float4*>(p + 32);
    a[3] = *reinterpret_cast<const float4*>(p + 36);
  };

  short8 bcur[6], bnext[6];
  auto loadB = [&](int kt, short8 bb[6]) {
#pragma unroll
    for (int i = 0; i < 3; i++) {
      const size_t toff = ((size_t)kt * 24 + (ng * 3 + i) * 2) * 512;
      bb[2 * i + 0] = *reinterpret_cast<const short8*>(Wl + toff);
      bb[2 * i + 1] = *reinterpret_cast<const short8*>(Wl + toff + 512);
    }
  };

  loadA(0, acur);
  loadB(0, bcur);

  for (int kt = 0; kt < 16; kt++) {
    if (kt < 15) {       // prefetch next tile while this one computes
      loadA(kt + 1, anext);
      loadB(kt + 1, bnext);
    }
    short8 af0, af1;
    {
      float* f = reinterpret_cast<float*>(acur);
#pragma unroll
      for (int j = 0; j < 4; j++) { af0[j] = (short)f2bf(f[j]); af0[4 + j] = (short)f2bf(f[4 + j]); }
#pragma unroll
      for (int j = 0; j < 4; j++) { af1[j] = (short)f2bf(f[8 + j]); af1[4 + j] = (short)f2bf(f[12 + j]); }
    }
    __builtin_amdgcn_s_setprio(1);
#pragma unroll
    for (int i = 0; i < 3; i++) {
      acc[i] = __builtin_amdgcn_mfma_f32_16x16x32_bf16(af0, bcur[2 * i + 0], acc[i], 0, 0, 0);
      acc[i] = __builtin_amdgcn_mfma_f32_16x16x32_bf16(af1, bcur[2 * i + 1], acc[i], 0, 0, 0);
    }
    __builtin_amdgcn_s_setprio(0);
#pragma unroll
    for (int i = 0; i < 4; i++) acur[i] = anext[i];
#pragma unroll
    for (int i = 0; i < 6; i++) bcur[i] = bnext[i];
  }

#pragma unroll
  for (int i = 0; i < 3; i++) {
    const int n = (ng * 3 + i) * 16 + q;
#pragma unroll
    for (int r = 0; r < 4; r++) {
      const int m = m0 + quad * 4 + r;
      const unsigned short hv = f2bf(acc[i][r]);
      if (n < 64) {
        Qg[(size_t)m * 64 + n] = hv;
      } else if (n < 128) {
        const int d = n - 64, s = m;
        const int b = s >> 11, srem = s & 2047, g = srem >> 4, qi = srem & 15;
        const int kk2 = d >> 5, quad2 = (d >> 3) & 3, j2 = d & 7;
        Kf[((((size_t)b * 128 + g) * 2 + kk2) * 64 + quad2 * 16 + qi) * 8 + j2] = hv;
      } else {
        const int d = n - 128, s = m;
        const int b = s >> 11, srem = s & 2047, kt2 = srem >> 6, s6 = srem & 63;
        const int kk2 = s6 >> 5, quad2 = (s6 >> 3) & 3, j2 = s6 & 7;
        const int dt = d >> 4, qi = d & 15;
        Vf[(((((size_t)b * 32 + kt2) * 4 + dt) * 2 + kk2) * 64 + quad2 * 16 + qi) * 8 + j2] = hv;
      }
    }
  }
}

// ---------------------------------------------------------------------------
// Kernel 3: flash attention, fixed-max softmax, barrier-free main loop with
// register K-prefetch. Grid 1024 (b = bid&7 -> XCD affinity), 256 thr = 4
// waves; wave w owns K-tiles [w*8, w*8+8) for the block's 16 q-rows.
// ---------------------------------------------------------------------------
__global__ __launch_bounds__(256, 3) void attn_kernel(const unsigned short* __restrict__ Qg,
                                                      const unsigned short* __restrict__ Kf,
                                                      const unsigned short* __restrict__ Vf,
                                                      const int* __restrict__ maskg,
                                                      float* __restrict__ outg) {
  __shared__ __align__(16) unsigned short Pl[4][16][72];  // 9216 B; reused as combine scratch

  const int tid = threadIdx.x;
  const int bid = blockIdx.x;
  const int b = bid & 7, qt = bid >> 3;
  const int q0 = qt * 16;
  const int w = tid >> 6, lane = tid & 63;
  const int q = lane & 15, quad = lane >> 4;

  const size_t qbase = ((size_t)b * 2048 + q0 + q) * 64 + quad * 8;
  const short8 qf0 = *reinterpret_cast<const short8*>(&Qg[qbase]);
  const short8 qf1 = *reinterpret_cast<const short8*>(&Qg[qbase + 32]);

  short8 onesf;
#pragma unroll
  for (int j = 0; j < 8; j++) onesf[j] = (short)0x3F80;  // bf16 1.0

  const unsigned short* Kb = Kf + (size_t)b * 131072 + lane * 8;
  const unsigned short* Vb = Vf + (size_t)b * 131072 + lane * 8;
  const int* mb = maskg + ((size_t)b * 2048 + q0 + quad) * 2048 + q * 4;

  v4f o_acc[4], l_acc;
#pragma unroll
  for (int dt = 0; dt < 4; dt++) o_acc[dt] = (v4f)(0.0f);
  l_acc = (v4f)(0.0f);

  const float SC = 0.125f * 1.4426950408889634f;  // 1/sqrt(64) * log2(e)
  const int kt0 = w * 8;

  auto loadK = [&](int kt, short8 kk[8]) {
#pragma unroll
    for (int f = 0; f < 8; f++)
      kk[f] = *reinterpret_cast<const short8*>(Kb + ((size_t)kt * 8 + f) * 512);
  };

  // initial mask tile -> zero-flag bits
  unsigned zb = 0;
  {
    int4 m4[4];
#pragma unroll
    for (int j = 0; j < 4; j++)
      m4[j] = *reinterpret_cast<const int4*>(mb + (size_t)j * 8192 + kt0 * 64);
#pragma unroll
    for (int j = 0; j < 4; j++)
      zb |= ((unsigned)(m4[j].x == 0) << (j * 4)) | ((unsigned)(m4[j].y == 0) << (j * 4 + 1)) |
            ((unsigned)(m4[j].z == 0) << (j * 4 + 2)) | ((unsigned)(m4[j].w == 0) << (j * 4 + 3));
  }

  short8 kcur[8], knext[8];
  loadK(kt0, kcur);

#pragma unroll
  for (int it = 0; it < 8; it++) {
    const int kt = kt0 + it;

    // prefetch next tile's mask
    int4 m4[4];
    if (it < 7) {
#pragma unroll
      for (int j = 0; j < 4; j++)
        m4[j] = *reinterpret_cast<const int4*>(mb + (size_t)j * 8192 + (kt + 1) * 64);
    }

    // S = Q K^T with the PREFETCHED fragments (no load latency here)
    v4f s_acc[4];
    __builtin_amdgcn_s_setprio(1);
#pragma unroll
    for (int nt = 0; nt < 4; nt++) {
      s_acc[nt] = __builtin_amdgcn_mfma_f32_16x16x32_bf16(qf0, kcur[nt * 2 + 0], (v4f)(0.0f), 0, 0, 0);
      s_acc[nt] = __builtin_amdgcn_mfma_f32_16x16x32_bf16(qf1, kcur[nt * 2 + 1], s_acc[nt], 0, 0, 0);
    }
    __builtin_amdgcn_s_setprio(0);

    // issue NEXT K-tile loads now: they hide under exp2 + LDS round-trip + PV
    if (it < 7) loadK(kt + 1, knext);

    // issue V loads now: hidden under the exp2 + P LDS round-trip
    short8 vf[8];
#pragma unroll
    for (int f = 0; f < 8; f++)
      vf[f] = *reinterpret_cast<const short8*>(Vb + ((size_t)kt * 8 + f) * 512);

    // fixed-max softmax numerator: p = exp2(s*SC); write P row-major
#pragma unroll
    for (int nt = 0; nt < 4; nt++)
#pragma unroll
      for (int r = 0; r < 4; r++)
        Pl[w][quad * 4 + r][nt * 16 + q] = f2bf(exp2f(s_acc[nt][r] * SC));

    // apply mask by zeroing P entries (dead branch when mask is all-nonzero)
    if (__any(zb != 0u)) {
#pragma unroll
      for (int j = 0; j < 4; j++)
#pragma unroll
        for (int c = 0; c < 4; c++)
          if ((zb >> (j * 4 + c)) & 1u) Pl[w][j * 4 + quad][q * 4 + c] = 0;
    }

    // read P as A fragments (same-wave RAW through LDS)
    const short8 pf0 = *reinterpret_cast<const short8*>(&Pl[w][q][quad * 8]);
    const short8 pf1 = *reinterpret_cast<const short8*>(&Pl[w][q][32 + quad * 8]);

    // O += P V ; l += P * ones
    __builtin_amdgcn_s_setprio(1);
#pragma unroll
    for (int dt = 0; dt < 4; dt++) {
      o_acc[dt] = __builtin_amdgcn_mfma_f32_16x16x32_bf16(pf0, vf[dt * 2 + 0], o_acc[dt], 0, 0, 0);
      o_acc[dt] = __builtin_amdgcn_mfma_f32_16x16x32_bf16(pf1, vf[dt * 2 + 1], o_acc[dt], 0, 0, 0);
    }
    l_acc = __builtin_amdgcn_mfma_f32_16x16x32_bf16(pf0, onesf, l_acc, 0, 0, 0);
    l_acc = __builtin_amdgcn_mfma_f32_16x16x32_bf16(pf1, onesf, l_acc, 0, 0, 0);
    __builtin_amdgcn_s_setprio(0);

    // rotate prefetch buffers; pack next tile's zero-bits
    if (it < 7) {
#pragma unroll
      for (int f = 0; f < 8; f++) kcur[f] = knext[f];
      zb = 0;
#pragma unroll
      for (int j = 0; j < 4; j++)
        zb |= ((unsigned)(m4[j].x == 0) << (j * 4)) | ((unsigned)(m4[j].y == 0) << (j * 4 + 1)) |
              ((unsigned)(m4[j].z == 0) << (j * 4 + 2)) | ((unsigned)(m4[j].w == 0) << (j * 4 + 3));
    }
  }

  // ---- tree combine of 4 waves' (o,l) through LDS (reusing Pl) ----
  __syncthreads();
  float* Osf = reinterpret_cast<float*>(&Pl[0][0][0]);  // [2][16][68] f32
  float* Lsf = Osf + 2 * 16 * 68;                       // [2][16] f32

  if (w >= 2) {
    const int wi = w - 2;
#pragma unroll
    for (int r = 0; r < 4; r++) {
      const int row = quad * 4 + r;
#pragma unroll
      for (int dt = 0; dt < 4; dt++) Osf[(wi * 16 + row) * 68 + dt * 16 + q] = o_acc[dt][r];
      if (q == 0) Lsf[wi * 16 + row] = l_acc[r];
    }
  }
  __syncthreads();
  if (w < 2) {
#pragma unroll
    for (int r = 0; r < 4; r++) {
      const int row = quad * 4 + r;
#pragma unroll
      for (int dt = 0; dt < 4; dt++) o_acc[dt][r] += Osf[(w * 16 + row) * 68 + dt * 16 + q];
      l_acc[r] += Lsf[w * 16 + row];
    }
  }
  __syncthreads();
  if (w == 1) {
#pragma unroll
    for (int r = 0; r < 4; r++) {
      const int row = quad * 4 + r;
#pragma unroll
      for (int dt = 0; dt < 4; dt++) Osf[row * 68 + dt * 16 + q] = o_acc[dt][r];
      if (q == 0) Lsf[row] = l_acc[r];
    }
  }
  __syncthreads();
  if (w == 0) {
#pragma unroll
    for (int r = 0; r < 4; r++) {
      const int row = quad * 4 + r;
      const float inv = 1.0f / (l_acc[r] + Lsf[row]);
      const size_t orow = ((size_t)b * 2048 + q0 + row) * 64;
#pragma unroll
      for (int dt = 0; dt < 4; dt++)
        outg[orow + dt * 16 + q] = (o_acc[dt][r] + Osf[row * 68 + dt * 16 + q]) * inv;
    }
  }
}

// ---------------------------------------------------------------------------
extern "C" void kernel_launch(void* const* d_in, const int* in_sizes, int n_in,
                              void* d_out, int out_size, void* d_ws, size_t ws_size,
                              hipStream_t stream) {
  const float* x = (const float*)d_in[0];
  const int* mask = (const int*)d_in[1];
  const float* Wq = (const float*)d_in[2];
  const float* Wk = (const float*)d_in[3];
  const float* Wv = (const float*)d_in[4];
  float* out = (float*)d_out;

  char* ws = (char*)d_ws;
  unsigned short* Qg = (unsigned short*)(ws);
  unsigned short* Kf = (unsigned short*)(ws + (size_t)(2 << 20));
  unsigned short* Vf = (unsigned short*)(ws + (size_t)(4 << 20));
  unsigned short* Wf = (unsigned short*)(ws + (size_t)(6 << 20));

  prep_wf<<<192, 256, 0, stream>>>(Wq, Wk, Wv, Wf);
  proj_kernel<<<512, 512, 0, stream>>>(x, Wf, Qg, Kf, Vf);
  attn_kernel<<<1024, 256, 0, stream>>>(Qg, Kf, Vf, mask, out);
}

// Round 4
// 293.334 us; speedup vs baseline: 1.0269x; 1.0055x over previous
//
#include <hip/hip_runtime.h>
#include <hip/hip_bf16.h>
#include <math.h>

// ---------------------------------------------------------------------------
// AttentionHead: B=8, S=2048, E=1024, D=64
// R4 == R3 resubmit (round-3 bench was an infra failure, not a kernel fail).
// (1) mask hoisted OUT of attn: fused prep kernel streams the 128MB int32
// mask once at copy BW and emits per-(qtile,ktile,lane) 16-bit zero-flag
// words (zbg, 4MB). attn's mask cost becomes one coalesced 2B load/iter,
// preloaded for all 8 iters. (2) WAR register prefetch (reload into the SAME
// regs after the consuming MFMAs) replaces double buffers in attn-K and
// proj-B: same prefetch distance, -32/-24 VGPRs -> no spill risk.
// attn ~140 VGPR @(256,3); proj ~90 VGPR @(512,4) (2 blocks/CU).
// ws: Qg @0MB | Kf frag @2MB | Vf frag @4MB | Wf frag @6MB | zbg @8MB (4MB)
// Requires ws_size >= 12MB (harness provides 512MB).
// ---------------------------------------------------------------------------

typedef __attribute__((ext_vector_type(8))) short short8;
typedef __attribute__((ext_vector_type(4))) float v4f;

__device__ __forceinline__ unsigned short f2bf(float f) {
  unsigned int u = __float_as_uint(f);
  unsigned int r = (u + 0x7fffu + ((u >> 16) & 1u)) >> 16;
  return (unsigned short)r;
}

// ---------------------------------------------------------------------------
// Kernel 1: fused prep. (a) mask -> zbg zero-flag words: thread t covers the
// 16 mask elements that attn-lane (t&63) tests at q-tile (t>>11)&127, k-tile
// (t>>6)&31, batch t>>18; bit j*4+c = (mask[qt*16+j*4+quad][kt*64+q*4+c]==0).
// (b) threads t<49152: Wq/Wk/Wv -> Wf proj fragment order (coalesced float4).
// Grid 8192 x 256.
// ---------------------------------------------------------------------------
__global__ __launch_bounds__(256) void prep_kernel(const float* __restrict__ Wq,
                                                   const float* __restrict__ Wk,
                                                   const float* __restrict__ Wv,
                                                   const int* __restrict__ maskg,
                                                   unsigned short* __restrict__ Wf,
                                                   unsigned short* __restrict__ zbg) {
  const int t = blockIdx.x * 256 + threadIdx.x;  // 0 .. 2097151
  const int lane = t & 63, kt = (t >> 6) & 31, qt = (t >> 11) & 127, b = t >> 18;
  const int q = lane & 15, quad = lane >> 4;
  const int* mp = maskg + ((size_t)(b * 2048 + qt * 16 + quad)) * 2048 + kt * 64 + q * 4;
  unsigned zb = 0;
#pragma unroll
  for (int j = 0; j < 4; j++) {
    int4 m4 = *reinterpret_cast<const int4*>(mp + (size_t)j * 8192);
    zb |= ((unsigned)(m4.x == 0) << (j * 4)) | ((unsigned)(m4.y == 0) << (j * 4 + 1)) |
          ((unsigned)(m4.z == 0) << (j * 4 + 2)) | ((unsigned)(m4.w == 0) << (j * 4 + 3));
  }
  zbg[t] = (unsigned short)zb;

  const bool doW = (t < 49152);
  if (doW) {  // Wf part: 4 consecutive floats of one W row per thread
    int e0 = t * 4;
    int m = e0 >> 16;      // which matrix (0..2)
    int rem = e0 & 65535;  // element within 64K-float matrix
    int k = rem >> 6, n0 = rem & 63;
    const float* W = (m == 0) ? Wq : (m == 1 ? Wk : Wv);
    float4 f4 = *reinterpret_cast<const float4*>(W + rem);
    int kt2 = k >> 6, rr = k & 63;
    int kk = rr >> 5, quad2 = (rr >> 3) & 3, j = k & 7;
    int cbase = kt2 * 24 + kk;
    float f[4] = {f4.x, f4.y, f4.z, f4.w};
#pragma unroll
    for (int c = 0; c < 4; c++) {
      int N = m * 64 + n0 + c;
      int nt = N >> 4, qq = N & 15;
      int o = (((cbase + nt * 2) << 6) | (quad2 * 16 + qq)) * 8 + j;
      Wf[o] = f2bf(f[c]);
    }
  }
}

// ---------------------------------------------------------------------------
// Kernel 2: QKV projection, barrier-free, WAR-prefetched B (single buffer).
// Grid 512 x 512 thr = 8 waves: (rg = w>>2: 16-row group) x (ng = w&3: 3
// n-tiles). (512,4): VGPR<=128 -> 2 blocks/CU, 16 waves/CU.
// ---------------------------------------------------------------------------
__global__ __launch_bounds__(512, 4) void proj_kernel(const float* __restrict__ x,
                                                      const unsigned short* __restrict__ Wf,
                                                      unsigned short* __restrict__ Qg,
                                                      unsigned short* __restrict__ Kf,
                                                      unsigned short* __restrict__ Vf) {
  const int tid = threadIdx.x;
  const int w = tid >> 6;
  const int lane = tid & 63;
  const int q = lane & 15, quad = lane >> 4;
  const int rg = w >> 2, ng = w & 3;
  const int m0 = blockIdx.x * 32 + rg * 16;

  const float* xrow = x + (size_t)(m0 + q) * 1024 + quad * 8;
  const unsigned short* Wl = Wf + lane * 8;

  v4f acc[3];
#pragma unroll
  for (int i = 0; i < 3; i++) acc[i] = (v4f)(0.0f);

  float4 acur[4], anext[4];
  auto loadA = [&](int kt, float4 a[4]) {
    const float* p = xrow + kt * 64;
    a[0] = *reinterpret_cast<const float4*>(p);
    a[1] = *reinterpret_cast<const float4*>(p + 4);
    a[2] = *reinterpret_cast<const float4*>(p + 32);
    a[3] = *reinterpret_cast<const float4*>(p + 36);
  };

  short8 bcur[6];
  auto loadB = [&](int kt, short8 bb[6]) {
#pragma unroll
    for (int i = 0; i < 3; i++) {
      const size_t toff = ((size_t)kt * 24 + (ng * 3 + i) * 2) * 512;
      bb[2 * i + 0] = *reinterpret_cast<const short8*>(Wl + toff);
      bb[2 * i + 1] = *reinterpret_cast<const short8*>(Wl + toff + 512);
    }
  };

  loadA(0, acur);
  loadB(0, bcur);

  for (int kt = 0; kt < 16; kt++) {
    if (kt < 15) loadA(kt + 1, anext);
    short8 af0, af1;
    {
      float* f = reinterpret_cast<float*>(acur);
#pragma unroll
      for (int j = 0; j < 4; j++) { af0[j] = (short)f2bf(f[j]); af0[4 + j] = (short)f2bf(f[4 + j]); }
#pragma unroll
      for (int j = 0; j < 4; j++) { af1[j] = (short)f2bf(f[8 + j]); af1[4 + j] = (short)f2bf(f[12 + j]); }
    }
    __builtin_amdgcn_s_setprio(1);
#pragma unroll
    for (int i = 0; i < 3; i++) {
      acc[i] = __builtin_amdgcn_mfma_f32_16x16x32_bf16(af0, bcur[2 * i + 0], acc[i], 0, 0, 0);
      acc[i] = __builtin_amdgcn_mfma_f32_16x16x32_bf16(af1, bcur[2 * i + 1], acc[i], 0, 0, 0);
    }
    __builtin_amdgcn_s_setprio(0);
    // WAR prefetch: reload next tile's B into the SAME regs (issues after the
    // MFMAs that read them; consumed one full iteration later)
    if (kt < 15) loadB(kt + 1, bcur);
#pragma unroll
    for (int i = 0; i < 4; i++) acur[i] = anext[i];
  }

#pragma unroll
  for (int i = 0; i < 3; i++) {
    const int n = (ng * 3 + i) * 16 + q;
#pragma unroll
    for (int r = 0; r < 4; r++) {
      const int m = m0 + quad * 4 + r;
      const unsigned short hv = f2bf(acc[i][r]);
      if (n < 64) {
        Qg[(size_t)m * 64 + n] = hv;
      } else if (n < 128) {
        const int d = n - 64, s = m;
        const int b = s >> 11, srem = s & 2047, g = srem >> 4, qi = srem & 15;
        const int kk2 = d >> 5, quad2 = (d >> 3) & 3, j2 = d & 7;
        Kf[((((size_t)b * 128 + g) * 2 + kk2) * 64 + quad2 * 16 + qi) * 8 + j2] = hv;
      } else {
        const int d = n - 128, s = m;
        const int b = s >> 11, srem = s & 2047, kt2 = srem >> 6, s6 = srem & 63;
        const int kk2 = s6 >> 5, quad2 = (s6 >> 3) & 3, j2 = s6 & 7;
        const int dt = d >> 4, qi = d & 15;
        Vf[(((((size_t)b * 32 + kt2) * 4 + dt) * 2 + kk2) * 64 + quad2 * 16 + qi) * 8 + j2] = hv;
      }
    }
  }
}

// ---------------------------------------------------------------------------
// Kernel 3: flash attention, fixed-max softmax, barrier-free main loop.
// Grid 1024 (b = bid&7 -> XCD affinity), 256 thr = 4 waves; wave w owns
// K-tiles [w*8, w*8+8) for the block's 16 q-rows. K: WAR register prefetch.
// Mask: 8 preloaded zbg words (2B/lane/iter), zero-apply behind __any().
// ---------------------------------------------------------------------------
__global__ __launch_bounds__(256, 3) void attn_kernel(const unsigned short* __restrict__ Qg,
                                                      const unsigned short* __restrict__ Kf,
                                                      const unsigned short* __restrict__ Vf,
                                                      const unsigned short* __restrict__ zbg,
                                                      float* __restrict__ outg) {
  __shared__ __align__(16) unsigned short Pl[4][16][72];  // 9216 B; reused as combine scratch

  const int tid = threadIdx.x;
  const int bid = blockIdx.x;
  const int b = bid & 7, qt = bid >> 3;
  const int q0 = qt * 16;
  const int w = tid >> 6, lane = tid & 63;
  const int q = lane & 15, quad = lane >> 4;

  const size_t qbase = ((size_t)b * 2048 + q0 + q) * 64 + quad * 8;
  const short8 qf0 = *reinterpret_cast<const short8*>(&Qg[qbase]);
  const short8 qf1 = *reinterpret_cast<const short8*>(&Qg[qbase + 32]);

  short8 onesf;
#pragma unroll
  for (int j = 0; j < 8; j++) onesf[j] = (short)0x3F80;  // bf16 1.0

  const unsigned short* Kb = Kf + (size_t)b * 131072 + lane * 8;
  const unsigned short* Vb = Vf + (size_t)b * 131072 + lane * 8;

  v4f o_acc[4], l_acc;
#pragma unroll
  for (int dt = 0; dt < 4; dt++) o_acc[dt] = (v4f)(0.0f);
  l_acc = (v4f)(0.0f);

  const float SC = 0.125f * 1.4426950408889634f;  // 1/sqrt(64) * log2(e)
  const int kt0 = w * 8;

  // preload this wave's 8 mask zero-flag words (coalesced 128B/instr)
  unsigned short zbs[8];
  {
    const unsigned short* zbp = zbg + (((size_t)b * 128 + qt) * 32 + kt0) * 64 + lane;
#pragma unroll
    for (int it = 0; it < 8; it++) zbs[it] = zbp[it * 64];
  }

  auto loadK = [&](int kt, short8 kk[8]) {
#pragma unroll
    for (int f = 0; f < 8; f++)
      kk[f] = *reinterpret_cast<const short8*>(Kb + ((size_t)kt * 8 + f) * 512);
  };

  short8 kcur[8];
  loadK(kt0, kcur);

#pragma unroll
  for (int it = 0; it < 8; it++) {
    const int kt = kt0 + it;

    // S = Q K^T with the prefetched fragments
    v4f s_acc[4];
    __builtin_amdgcn_s_setprio(1);
#pragma unroll
    for (int nt = 0; nt < 4; nt++) {
      s_acc[nt] = __builtin_amdgcn_mfma_f32_16x16x32_bf16(qf0, kcur[nt * 2 + 0], (v4f)(0.0f), 0, 0, 0);
      s_acc[nt] = __builtin_amdgcn_mfma_f32_16x16x32_bf16(qf1, kcur[nt * 2 + 1], s_acc[nt], 0, 0, 0);
    }
    __builtin_amdgcn_s_setprio(0);

    // WAR prefetch: next K-tile into the SAME regs (issues after the MFMAs
    // above; consumed next iteration, hidden under exp2 + LDS + PV)
    if (it < 7) loadK(kt + 1, kcur);

    // V loads: hidden under the exp2 + P LDS round-trip
    short8 vf[8];
#pragma unroll
    for (int f = 0; f < 8; f++)
      vf[f] = *reinterpret_cast<const short8*>(Vb + ((size_t)kt * 8 + f) * 512);

    // fixed-max softmax numerator: p = exp2(s*SC); write P row-major
#pragma unroll
    for (int nt = 0; nt < 4; nt++)
#pragma unroll
      for (int r = 0; r < 4; r++)
        Pl[w][quad * 4 + r][nt * 16 + q] = f2bf(exp2f(s_acc[nt][r] * SC));

    // apply mask by zeroing P entries (dead branch when mask is all-nonzero)
    if (__any(zbs[it] != 0)) {
#pragma unroll
      for (int j = 0; j < 4; j++)
#pragma unroll
        for (int c = 0; c < 4; c++)
          if ((zbs[it] >> (j * 4 + c)) & 1u) Pl[w][j * 4 + quad][q * 4 + c] = 0;
    }

    // read P as A fragments (same-wave RAW through LDS)
    const short8 pf0 = *reinterpret_cast<const short8*>(&Pl[w][q][quad * 8]);
    const short8 pf1 = *reinterpret_cast<const short8*>(&Pl[w][q][32 + quad * 8]);

    // O += P V ; l += P * ones
    __builtin_amdgcn_s_setprio(1);
#pragma unroll
    for (int dt = 0; dt < 4; dt++) {
      o_acc[dt] = __builtin_amdgcn_mfma_f32_16x16x32_bf16(pf0, vf[dt * 2 + 0], o_acc[dt], 0, 0, 0);
      o_acc[dt] = __builtin_amdgcn_mfma_f32_16x16x32_bf16(pf1, vf[dt * 2 + 1], o_acc[dt], 0, 0, 0);
    }
    l_acc = __builtin_amdgcn_mfma_f32_16x16x32_bf16(pf0, onesf, l_acc, 0, 0, 0);
    l_acc = __builtin_amdgcn_mfma_f32_16x16x32_bf16(pf1, onesf, l_acc, 0, 0, 0);
    __builtin_amdgcn_s_setprio(0);
  }

  // ---- tree combine of 4 waves' (o,l) through LDS (reusing Pl) ----
  __syncthreads();
  float* Osf = reinterpret_cast<float*>(&Pl[0][0][0]);  // [2][16][68] f32
  float* Lsf = Osf + 2 * 16 * 68;                       // [2][16] f32

  if (w >= 2) {
    const int wi = w - 2;
#pragma unroll
    for (int r = 0; r < 4; r++) {
      const int row = quad * 4 + r;
#pragma unroll
      for (int dt = 0; dt < 4; dt++) Osf[(wi * 16 + row) * 68 + dt * 16 + q] = o_acc[dt][r];
      if (q == 0) Lsf[wi * 16 + row] = l_acc[r];
    }
  }
  __syncthreads();
  if (w < 2) {
#pragma unroll
    for (int r = 0; r < 4; r++) {
      const int row = quad * 4 + r;
#pragma unroll
      for (int dt = 0; dt < 4; dt++) o_acc[dt][r] += Osf[(w * 16 + row) * 68 + dt * 16 + q];
      l_acc[r] += Lsf[w * 16 + row];
    }
  }
  __syncthreads();
  if (w == 1) {
#pragma unroll
    for (int r = 0; r < 4; r++) {
      const int row = quad * 4 + r;
#pragma unroll
      for (int dt = 0; dt < 4; dt++) Osf[row * 68 + dt * 16 + q] = o_acc[dt][r];
      if (q == 0) Lsf[row] = l_acc[r];
    }
  }
  __syncthreads();
  if (w == 0) {
#pragma unroll
    for (int r = 0; r < 4; r++) {
      const int row = quad * 4 + r;
      const float inv = 1.0f / (l_acc[r] + Lsf[row]);
      const size_t orow = ((size_t)b * 2048 + q0 + row) * 64;
#pragma unroll
      for (int dt = 0; dt < 4; dt++)
        outg[orow + dt * 16 + q] = (o_acc[dt][r] + Osf[row * 68 + dt * 16 + q]) * inv;
    }
  }
}

// ---------------------------------------------------------------------------
extern "C" void kernel_launch(void* const* d_in, const int* in_sizes, int n_in,
                              void* d_out, int out_size, void* d_ws, size_t ws_size,
                              hipStream_t stream) {
  const float* x = (const float*)d_in[0];
  const int* mask = (const int*)d_in[1];
  const float* Wq = (const float*)d_in[2];
  const float* Wk = (const float*)d_in[3];
  const float* Wv = (const float*)d_in[4];
  float* out = (float*)d_out;

  char* ws = (char*)d_ws;
  unsigned short* Qg = (unsigned short*)(ws);
  unsigned short* Kf = (unsigned short*)(ws + (size_t)(2 << 20));
  unsigned short* Vf = (unsigned short*)(ws + (size_t)(4 << 20));
  unsigned short* Wf = (unsigned short*)(ws + (size_t)(6 << 20));
  unsigned short* zbg = (unsigned short*)(ws + (size_t)(8 << 20));

  prep_kernel<<<8192, 256, 0, stream>>>(Wq, Wk, Wv, mask, Wf, zbg);
  proj_kernel<<<512, 512, 0, stream>>>(x, Wf, Qg, Kf, Vf);
  attn_kernel<<<1024, 256, 0, stream>>>(Qg, Kf, Vf, zbg, out);
}